// Round 5
// baseline (441.171 us; speedup 1.0000x reference)
//
#include <hip/hip_runtime.h>
#include <hip/hip_bf16.h>
#include <math.h>

// ---------------------------------------------------------------------------
// Problem constants
// ---------------------------------------------------------------------------
constexpr int B = 8;
constexpr int N = 2048;
constexpr int KNN = 20;
constexpr int H = 128;
constexpr int P = 3 * N;  // 6144 pixels per batch

// ws layout (float offsets)
constexpr int OWNPOS = 0;         // 64x3 normalized W_pos (pad 256)
constexpr int OWN1   = 256;       // 128x64 fp32 normalized
constexpr int OWN2   = 8448;      // 128x256
constexpr int OWN3   = 41216;     // 128x256
constexpr int OPS1   = 73984;     // poolsum1 [b][128][3]
constexpr int OPS2   = 77056;     // poolsum2
constexpr int OBIAS2 = 80128;     // bias2 [b][256][3] = 6144
constexpr int OBIAS3 = 86272;     // bias3
constexpr int OIDX   = 92416;     // knn idx: 8*2048*20 ints
constexpr int OWB1   = 420096;    // Wbig1 256x128 bf16 (16384 f)
constexpr int OWB2   = 436480;    // Wbig2 256x256 bf16 (32768 f)
constexpr int OWB3   = 469248;    // Wbig3 256x256 bf16 (32768 f)
constexpr int ONET0  = 502016;    // net0 fp32 [b][64][3][N] (3145728 f)
constexpr int OXP0   = 3647744;   // Xp0 bf16 [b][P][128]  (3145728 f-equiv)
constexpr int OXP1   = 6793472;   // Xp1 bf16 [b][P][256]  (6291456 f-equiv)
constexpr int OXP2   = ONET0;     // Xp2 reuses net0+Xp0 region (both dead)
// total 13,084,928 floats ~= 52.3 MB

typedef __attribute__((ext_vector_type(8))) short bf16x8;
typedef __attribute__((ext_vector_type(4))) float f32x4;

__device__ __forceinline__ unsigned short f2bf(float x) {
  __hip_bfloat16 h = __float2bfloat16(x);
  return *(unsigned short*)&h;
}
__device__ __forceinline__ float bf2f(unsigned short u) {
  __hip_bfloat16 h;
  *(unsigned short*)&h = u;
  return __bfloat162float(h);
}
// pack x as (hi, lo) bf16 pair in one uint (hi at low halfword = lower addr)
__device__ __forceinline__ unsigned int packhl(float x) {
  unsigned short hi = f2bf(x);
  float lo = x - bf2f(hi);
  unsigned short ls = f2bf(lo);
  return (unsigned)hi | ((unsigned)ls << 16);
}

// ---------------------------------------------------------------------------
// Wave-wide bitonic sort of 64 (value,index) pairs, descending, tie->low idx.
// ---------------------------------------------------------------------------
__device__ __forceinline__ void wave_sort64(float& v, int& m, int lane) {
#pragma unroll
  for (int k = 2; k <= 64; k <<= 1) {
#pragma unroll
    for (int j = k >> 1; j > 0; j >>= 1) {
      float pv = __shfl_xor(v, j);
      int   pm = __shfl_xor(m, j);
      bool iam_lower   = (lane & j) == 0;
      bool dir_desc    = (lane & k) == 0;
      bool p_better    = (pv > v) || (pv == v && pm < m);
      bool want_better = (dir_desc == iam_lower);
      bool take        = (p_better == want_better);
      v = take ? pv : v;
      m = take ? pm : m;
    }
  }
}

// ---------------------------------------------------------------------------
// K1: normalize W rows (rows sum to 1).
// ---------------------------------------------------------------------------
__global__ __launch_bounds__(256) void norm_rows_kernel(
    const float* __restrict__ Wpos, const float* __restrict__ W1,
    const float* __restrict__ W2, const float* __restrict__ W3,
    float* __restrict__ ws) {
  int r = blockIdx.x * 4 + (threadIdx.x >> 6);
  int lane = threadIdx.x & 63;
  const float* src;
  float* dst;
  int C;
  if (r < 64)       { src = Wpos + r * 3;          dst = ws + OWNPOS + r * 3;          C = 3;   }
  else if (r < 192) { int rr = r - 64;  src = W1 + rr * 64;  dst = ws + OWN1 + rr * 64;  C = 64;  }
  else if (r < 320) { int rr = r - 192; src = W2 + rr * 256; dst = ws + OWN2 + rr * 256; C = 256; }
  else              { int rr = r - 320; src = W3 + rr * 256; dst = ws + OWN3 + rr * 256; C = 256; }
  float s = 0.f;
  for (int i = lane; i < C; i += 64) s += src[i];
#pragma unroll
  for (int off = 32; off > 0; off >>= 1) s += __shfl_xor(s, off);
  for (int i = lane; i < C; i += 64) dst[i] = src[i] / s;
}

// ---------------------------------------------------------------------------
// K1b: pack stacked [Wn ; D] (first C cols) into bf16 hi/lo, K doubled.
// dst[m][2c]=hi, dst[m][2c+1]=lo.  rows 0..127 = Wn, 128..255 = D (raw).
// ---------------------------------------------------------------------------
__global__ __launch_bounds__(256) void pack_w_kernel(
    const float* __restrict__ Wn, const float* __restrict__ Draw,
    int C, int ldw, unsigned short* __restrict__ dst) {
  int idx = blockIdx.x * 256 + threadIdx.x;
  if (idx >= 256 * C) return;
  int m = idx / C, c = idx % C;
  float x = (m < 128) ? Wn[m * ldw + c] : Draw[(m - 128) * ldw + c];
  *(unsigned int*)(dst + (size_t)(m * C + c) * 2) = packhl(x);
}

// ---------------------------------------------------------------------------
// K2: exact top-20 KNN (unchanged from round 4).
// ---------------------------------------------------------------------------
__global__ __launch_bounds__(256, 4) void knn_kernel(const float* __restrict__ pc,
                                                     int* __restrict__ idxout) {
  __shared__ float4 spt[N];
  __shared__ unsigned short sbuf[4][512];
  int tid = threadIdx.x;
  int b = blockIdx.y;
  const float* pcb = pc + b * N * 3;
  for (int i = tid; i < N; i += 256) {
    float x = pcb[i * 3 + 0], y = pcb[i * 3 + 1], z = pcb[i * 3 + 2];
    float xx = __fadd_rn(__fadd_rn(__fmul_rn(x, x), __fmul_rn(y, y)), __fmul_rn(z, z));
    spt[i] = make_float4(2.f * x, 2.f * y, 2.f * z, xx);
  }
  __syncthreads();
  int wv = tid >> 6, lane = tid & 63;
  int q = blockIdx.x * 4 + wv;
  float4 qp = spt[q];
  float qx = 0.5f * qp.x, qy = 0.5f * qp.y, qz = 0.5f * qp.z, qxx = qp.w;

  float dv[32];
  float lmax = -INFINITY;
#pragma unroll
  for (int i = 0; i < 32; ++i) {
    float4 m = spt[i * 64 + lane];
    float A = __fadd_rn(__fadd_rn(__fmul_rn(m.x, qx), __fmul_rn(m.y, qy)),
                        __fmul_rn(m.z, qz));
    float d = __fsub_rn(__fsub_rn(A, qxx), m.w);
    dv[i] = d;
    lmax = fmaxf(lmax, d);
  }
  unsigned u = __float_as_uint(lmax);
  u = u ^ ((u >> 31) ? 0xFFFFFFFFu : 0x80000000u);
  unsigned prefix = 0u;
#pragma unroll
  for (int bit = 31; bit >= 0; --bit) {
    unsigned test = prefix | (1u << bit);
    int cnt = (int)__popcll(__ballot(u >= test));
    if (cnt >= KNN) prefix = test;
  }
  float tval = __uint_as_float((prefix >> 31) ? (prefix ^ 0x80000000u) : ~prefix);

  int base = 0;
#pragma unroll
  for (int i = 0; i < 32; ++i) {
    bool s = dv[i] >= tval;
    unsigned long long mk = __ballot(s);
    if (s) {
      int pos = base + (int)__popcll(mk & ((1ull << lane) - 1ull));
      if (pos < 512) sbuf[wv][pos] = (unsigned short)(i * 64 + lane);
    }
    base += (int)__popcll(mk);
  }
  int S = base;

  auto distOf = [&](int m) -> float {
    float4 mp = spt[m];
    float A = __fadd_rn(__fadd_rn(__fmul_rn(mp.x, qx), __fmul_rn(mp.y, qy)),
                        __fmul_rn(mp.z, qz));
    return __fsub_rn(__fsub_rn(A, qxx), mp.w);
  };

  float cv = -INFINITY;
  int cm = 0x7fffffff;
  if (S <= 64) {
    if (lane < S) { cm = sbuf[wv][lane]; cv = distOf(cm); }
    wave_sort64(cv, cm, lane);
  } else if (S <= 512) {
    int pos = 0;
    while (pos < S) {
      if (lane >= KNN) {
        int t = pos + lane - KNN;
        if (t < S) { cm = sbuf[wv][t]; cv = distOf(cm); }
        else       { cm = 0x7fffffff;  cv = -INFINITY; }
      }
      wave_sort64(cv, cm, lane);
      pos += 64 - KNN;
    }
  } else {
    int pos = 0;
    while (pos < N) {
      if (lane >= KNN) {
        int t = pos + lane - KNN;
        if (t < N) { cm = t; cv = distOf(t); }
        else       { cm = 0x7fffffff; cv = -INFINITY; }
      }
      wave_sort64(cv, cm, lane);
      pos += 64 - KNN;
    }
  }
  if (lane < KNN) idxout[(b * N + q) * KNN + lane] = cm;
}

// ---------------------------------------------------------------------------
// K3: edge features -> pos layer (64ch) -> VN-LeakyReLU -> mean over k.
// net0[b][c][v][n]  (unchanged)
// ---------------------------------------------------------------------------
__global__ __launch_bounds__(256) void edge_pos_kernel(
    const float* __restrict__ pc, const int* __restrict__ knn,
    const float* __restrict__ Wn, const float* __restrict__ Dp,
    float* __restrict__ net0) {
  int tid = threadIdx.x;
  int og = blockIdx.x, nt = blockIdx.y, b = blockIdx.z;
  int n = nt * 256 + tid;
  const float* pcb = pc + b * N * 3;
  float cx = pcb[n * 3 + 0], cy = pcb[n * 3 + 1], cz = pcb[n * 3 + 2];

  float w[4][3], dw[4][3], ax[4], ay[4], az[4];
#pragma unroll
  for (int j = 0; j < 4; ++j) {
    int o = og * 4 + j;
    w[j][0] = Wn[o * 3 + 0]; w[j][1] = Wn[o * 3 + 1]; w[j][2] = Wn[o * 3 + 2];
    dw[j][0] = Dp[o * 3 + 0]; dw[j][1] = Dp[o * 3 + 1]; dw[j][2] = Dp[o * 3 + 2];
    ax[j] = 0.f; ay[j] = 0.f; az[j] = 0.f;
  }
  const int* kn = knn + (b * N + n) * KNN;
  for (int k = 0; k < KNN; ++k) {
    int m = kn[k];
    float nx = pcb[m * 3 + 0], ny = pcb[m * 3 + 1], nz = pcb[m * 3 + 2];
    float ex = nx - cx, ey = ny - cy, ez = nz - cz;
    float rx = ny * cz - nz * cy;
    float ry = nz * cx - nx * cz;
    float rz = nx * cy - ny * cx;
#pragma unroll
    for (int j = 0; j < 4; ++j) {
      float px = fmaf(w[j][0], ex, fmaf(w[j][1], cx, w[j][2] * rx));
      float py = fmaf(w[j][0], ey, fmaf(w[j][1], cy, w[j][2] * ry));
      float pz = fmaf(w[j][0], ez, fmaf(w[j][1], cz, w[j][2] * rz));
      float dx = fmaf(dw[j][0], ex, fmaf(dw[j][1], cx, dw[j][2] * rx));
      float dy = fmaf(dw[j][0], ey, fmaf(dw[j][1], cy, dw[j][2] * ry));
      float dz = fmaf(dw[j][0], ez, fmaf(dw[j][1], cz, dw[j][2] * rz));
      float dot = fmaf(px, dx, fmaf(py, dy, pz * dz));
      float dns = fmaf(dx, dx, fmaf(dy, dy, dz * dz));
      float f = (dot < 0.f) ? dot / (dns + 1e-6f) : 0.f;
      ax[j] += px - f * dx;
      ay[j] += py - f * dy;
      az[j] += pz - f * dz;
    }
  }
#pragma unroll
  for (int j = 0; j < 4; ++j) {
    int o = og * 4 + j;
    net0[((b * 64 + o) * 3 + 0) * N + n] = ax[j] * (1.f / 20.f);
    net0[((b * 64 + o) * 3 + 1) * N + n] = ay[j] * (1.f / 20.f);
    net0[((b * 64 + o) * 3 + 2) * N + n] = az[j] * (1.f / 20.f);
  }
}

// ---------------------------------------------------------------------------
// K3b: pack net0 fp32 -> Xp0 bf16 hi/lo, pixel layout p=(n>>4)*48+v*16+(n&15).
// ---------------------------------------------------------------------------
__global__ __launch_bounds__(256) void pack0_kernel(
    const float* __restrict__ net0, unsigned short* __restrict__ Xp0) {
  int g = blockIdx.x * 256 + threadIdx.x;  // B*N threads
  int b = g >> 11, n = g & 2047;
  int pbase = ((n >> 4) * 48) + (n & 15);
#pragma unroll
  for (int v = 0; v < 3; ++v) {
    unsigned short* dst = Xp0 + ((size_t)b * P + pbase + v * 16) * 128;
#pragma unroll 8
    for (int c = 0; c < 64; ++c) {
      float x = net0[((b * 64 + c) * 3 + v) * N + n];
      *(unsigned int*)(dst + 2 * c) = packhl(x);
    }
  }
}

// ---------------------------------------------------------------------------
// K5/K7: bias for pooled-concat half: bias[b][m][v] =
//   sum_c row[m][C+c] * poolsum[b][c][v] / N,  rows 0..127=Wn, 128..255=D.
// ---------------------------------------------------------------------------
__global__ __launch_bounds__(256) void bias_kernel(
    const float* __restrict__ Wn, const float* __restrict__ Draw,
    const float* __restrict__ ps, float* __restrict__ bias) {
  int idx = blockIdx.x * 256 + threadIdx.x;  // B*256*3
  if (idx >= B * 256 * 3) return;
  int v = idx % 3;
  int m = (idx / 3) & 255;
  int b = idx / 768;
  const float* row = ((m < 128) ? (Wn + m * 256) : (Draw + (m - 128) * 256)) + 128;
  const float* pp = ps + (size_t)b * 128 * 3 + v;
  float s = 0.f;
#pragma unroll 8
  for (int c = 0; c < 128; ++c) s = fmaf(row[c], pp[c * 3], s);
  bias[idx] = s * (1.f / 2048.f);
}

// ---------------------------------------------------------------------------
// K4/K6/K8: MFMA VNT layer.  D[256][48] = Wbig[256][K2] x Xtile[K2][48].
// Stacked rows: 0..127 = Wn (p), 128..255 = D (d).  bf16 hi/lo pairs (K2=2C).
// Pixel tile = 16 n x 3 v (n-frag f == v), so VN-LeakyReLU is lane-local:
// C/D layout col=lane&15 (=n), row=quad*4+reg (=o), pair (o, o+128) in
// m-frags (mi, mi+8) of the SAME wave (wave w owns frags {2w,2w+1,2w+8,2w+9}).
// Grid: B * 128 n-tiles = 1024 blocks, 4 waves each.
// Epilogue: pack activated output as next layer's bf16 hi/lo (scatter 4B),
// pool partial sums via 16-lane shfl + one atomic per (o,v).
// ---------------------------------------------------------------------------
template <int K2, bool HASPOOL, bool LAST>
__global__ __launch_bounds__(256, 4) void gemm_vnt_kernel(
    const unsigned short* __restrict__ Xp, const unsigned short* __restrict__ Wb,
    const float* __restrict__ bias, unsigned short* __restrict__ Xq,
    float* __restrict__ pool, float* __restrict__ outp) {
  constexpr int KS = K2 / 32;
  constexpr int LDR = K2 + 8;  // padded row stride (halves): +16B breaks bank aliasing
  __shared__ __align__(16) unsigned short xt[48 * LDR];
  __shared__ float sb[768];
  int tid = threadIdx.x;
  int bid = blockIdx.x;
  int b = bid >> 7;
  int nt = bid & 127;
  int p0 = nt * 48;

  // stage X tile [48][K2] -> LDS (rows padded)
  for (int ch = tid; ch < 48 * (K2 / 8); ch += 256) {
    int rp = ch / (K2 / 8), cc = ch % (K2 / 8);
    uint4 vv = *(const uint4*)(Xp + ((size_t)b * P + p0 + rp) * K2 + cc * 8);
    *(uint4*)(xt + rp * LDR + cc * 8) = vv;
  }
  if (HASPOOL) {
    for (int i = tid; i < 768; i += 256) sb[i] = bias[b * 768 + i];
  }
  __syncthreads();

  int w = tid >> 6, lane = tid & 63;
  int q = lane >> 4, cl = lane & 15;

  f32x4 acc[2][2][3] = {};  // [t][pd][v]
  const unsigned short* wbase = Wb + (size_t)cl * K2 + q * 8;
#pragma unroll 2
  for (int ks = 0; ks < KS; ++ks) {
    bf16x8 a[2][2], bb[3];
#pragma unroll
    for (int t = 0; t < 2; ++t)
#pragma unroll
      for (int pd = 0; pd < 2; ++pd) {
        int m0 = 32 * w + 16 * t + 128 * pd;
        a[t][pd] = *(const bf16x8*)(wbase + (size_t)m0 * K2 + ks * 32);
      }
#pragma unroll
    for (int v = 0; v < 3; ++v)
      bb[v] = *(const bf16x8*)(xt + (v * 16 + cl) * LDR + ks * 32 + q * 8);
#pragma unroll
    for (int t = 0; t < 2; ++t)
#pragma unroll
      for (int pd = 0; pd < 2; ++pd)
#pragma unroll
        for (int v = 0; v < 3; ++v)
          acc[t][pd][v] = __builtin_amdgcn_mfma_f32_16x16x32_bf16(
              a[t][pd], bb[v], acc[t][pd][v], 0, 0, 0);
  }

  // epilogue
#pragma unroll
  for (int t = 0; t < 2; ++t) {
#pragma unroll
    for (int r = 0; r < 4; ++r) {
      int o = 32 * w + 16 * t + 4 * q + r;
      float pv[3], dv[3];
#pragma unroll
      for (int v = 0; v < 3; ++v) {
        pv[v] = acc[t][0][v][r] + (HASPOOL ? sb[o * 3 + v] : 0.f);
        dv[v] = acc[t][1][v][r] + (HASPOOL ? sb[(128 + o) * 3 + v] : 0.f);
      }
      float dot = fmaf(pv[0], dv[0], fmaf(pv[1], dv[1], pv[2] * dv[2]));
      float dns = fmaf(dv[0], dv[0], fmaf(dv[1], dv[1], dv[2] * dv[2]));
      float f = (dot < 0.f) ? dot / (dns + 1e-6f) : 0.f;
      float res[3];
#pragma unroll
      for (int v = 0; v < 3; ++v) res[v] = pv[v] - f * dv[v];

      if (!LAST) {
#pragma unroll
        for (int v = 0; v < 3; ++v) {
          size_t addr = ((size_t)b * P + p0 + v * 16 + cl) * 256 + 2 * o;
          *(unsigned int*)(Xq + addr) = packhl(res[v]);
        }
      }
#pragma unroll
      for (int v = 0; v < 3; ++v) {
        float s = res[v];
        s += __shfl_xor(s, 1);
        s += __shfl_xor(s, 2);
        s += __shfl_xor(s, 4);
        s += __shfl_xor(s, 8);
        if (cl == 0) {
          if (LAST) atomicAdd(outp + b * 384 + o * 3 + v, s * (1.f / 2048.f));
          else      atomicAdd(pool + (b * 128 + o) * 3 + v, s);
        }
      }
    }
  }
}

// ---------------------------------------------------------------------------
// launch
// ---------------------------------------------------------------------------
extern "C" void kernel_launch(void* const* d_in, const int* in_sizes, int n_in,
                              void* d_out, int out_size, void* d_ws, size_t ws_size,
                              hipStream_t stream) {
  (void)in_sizes; (void)n_in; (void)out_size; (void)ws_size;
  const float* pc   = (const float*)d_in[0];
  const float* Wpos = (const float*)d_in[1];
  const float* Dpos = (const float*)d_in[2];
  const float* W1   = (const float*)d_in[3];
  const float* D1   = (const float*)d_in[4];
  const float* W2   = (const float*)d_in[5];
  const float* D2   = (const float*)d_in[6];
  const float* W3   = (const float*)d_in[7];
  const float* D3   = (const float*)d_in[8];
  float* out = (float*)d_out;
  float* ws  = (float*)d_ws;

  hipMemsetAsync(ws + OPS1, 0, 2 * 3072 * sizeof(float), stream);  // ps1+ps2
  hipMemsetAsync(out, 0, B * 384 * sizeof(float), stream);

  norm_rows_kernel<<<112, 256, 0, stream>>>(Wpos, W1, W2, W3, ws);
  pack_w_kernel<<<64, 256, 0, stream>>>(ws + OWN1, D1, 64, 64,
                                        (unsigned short*)(ws + OWB1));
  pack_w_kernel<<<128, 256, 0, stream>>>(ws + OWN2, D2, 128, 256,
                                         (unsigned short*)(ws + OWB2));
  pack_w_kernel<<<128, 256, 0, stream>>>(ws + OWN3, D3, 128, 256,
                                         (unsigned short*)(ws + OWB3));
  knn_kernel<<<dim3(N / 4, B), 256, 0, stream>>>(pc, (int*)(ws + OIDX));
  edge_pos_kernel<<<dim3(16, 8, 8), 256, 0, stream>>>(
      pc, (const int*)(ws + OIDX), ws + OWNPOS, Dpos, ws + ONET0);
  pack0_kernel<<<64, 256, 0, stream>>>(ws + ONET0, (unsigned short*)(ws + OXP0));
  // layer1: K2=128, no pooled half; -> Xp1 + ps1
  gemm_vnt_kernel<128, false, false><<<1024, 256, 0, stream>>>(
      (const unsigned short*)(ws + OXP0), (const unsigned short*)(ws + OWB1),
      nullptr, (unsigned short*)(ws + OXP1), ws + OPS1, nullptr);
  bias_kernel<<<24, 256, 0, stream>>>(ws + OWN2, D2, ws + OPS1, ws + OBIAS2);
  // layer2: -> Xp2 + ps2
  gemm_vnt_kernel<256, true, false><<<1024, 256, 0, stream>>>(
      (const unsigned short*)(ws + OXP1), (const unsigned short*)(ws + OWB2),
      ws + OBIAS2, (unsigned short*)(ws + OXP2), ws + OPS2, nullptr);
  bias_kernel<<<24, 256, 0, stream>>>(ws + OWN3, D3, ws + OPS2, ws + OBIAS3);
  // layer3: mean over N -> d_out
  gemm_vnt_kernel<256, true, true><<<1024, 256, 0, stream>>>(
      (const unsigned short*)(ws + OXP2), (const unsigned short*)(ws + OWB3),
      ws + OBIAS3, nullptr, nullptr, out);
}

// Round 6
// 253.237 us; speedup vs baseline: 1.7421x; 1.7421x over previous
//
#include <hip/hip_runtime.h>
#include <hip/hip_bf16.h>
#include <math.h>

// ---------------------------------------------------------------------------
// Problem constants
// ---------------------------------------------------------------------------
constexpr int B = 8;
constexpr int N = 2048;
constexpr int KNN = 20;
constexpr int H = 128;
constexpr int P = 3 * N;  // 6144 pixels per batch

// ws layout (float offsets)
constexpr int OWNPOS = 0;         // 64x3 normalized W_pos (pad 256)
constexpr int OWN1   = 256;       // 128x64 fp32 normalized
constexpr int OWN2   = 8448;      // 128x256
constexpr int OWN3   = 41216;     // 128x256
constexpr int OPS1   = 73984;     // poolsum1 shadows [8][B][128][3] = 24576
constexpr int OPS2   = 98560;     // poolsum2 shadows = 24576
constexpr int OOUTS  = 123136;    // out shadows [8][B][384] = 24576
constexpr int OBIAS2 = 147712;    // bias2 [b][256][3] = 6144
constexpr int OBIAS3 = 153856;    // bias3 = 6144
constexpr int OWB1   = 160000;    // Wbig1 256x128 bf16 hi/lo (16384 f)
constexpr int OWB2   = 176384;    // Wbig2 256x256 bf16 hi/lo (32768 f)
constexpr int OWB3   = 209152;    // Wbig3 256x256 bf16 hi/lo (32768 f)
constexpr int OIDX   = 241920;    // knn idx: 8*2048*20 ints = 327680
constexpr int ONET0  = 569600;    // net0 fp32 [b][64][3][N] (3145728 f)
constexpr int OXP0   = 3715328;   // Xp0 bf16 [b][P][128] (3145728 f-equiv)
constexpr int OXP1   = 6861056;   // Xp1 bf16 [b][P][256] (6291456 f-equiv)
constexpr int OXP2   = ONET0;     // Xp2 reuses net0+Xp0 (both dead by then)
// max extent 13,152,512 floats ~= 52.6 MB

typedef __attribute__((ext_vector_type(8))) short bf16x8;
typedef __attribute__((ext_vector_type(4))) float f32x4;

__device__ __forceinline__ unsigned short f2bf(float x) {
  __hip_bfloat16 h = __float2bfloat16(x);
  return *(unsigned short*)&h;
}
__device__ __forceinline__ float bf2f(unsigned short u) {
  __hip_bfloat16 h;
  *(unsigned short*)&h = u;
  return __bfloat162float(h);
}
// pack x as (hi, lo) bf16 pair in one uint (hi at lower address)
__device__ __forceinline__ unsigned int packhl(float x) {
  unsigned short hi = f2bf(x);
  float lo = x - bf2f(hi);
  unsigned short ls = f2bf(lo);
  return (unsigned)hi | ((unsigned)ls << 16);
}

// ---------------------------------------------------------------------------
// Wave-wide bitonic sort of 64 (value,index) pairs, descending, tie->low idx.
// ---------------------------------------------------------------------------
__device__ __forceinline__ void wave_sort64(float& v, int& m, int lane) {
#pragma unroll
  for (int k = 2; k <= 64; k <<= 1) {
#pragma unroll
    for (int j = k >> 1; j > 0; j >>= 1) {
      float pv = __shfl_xor(v, j);
      int   pm = __shfl_xor(m, j);
      bool iam_lower   = (lane & j) == 0;
      bool dir_desc    = (lane & k) == 0;
      bool p_better    = (pv > v) || (pv == v && pm < m);
      bool want_better = (dir_desc == iam_lower);
      bool take        = (p_better == want_better);
      v = take ? pv : v;
      m = take ? pm : m;
    }
  }
}

// ---------------------------------------------------------------------------
// K1: normalize W rows (rows sum to 1).
// ---------------------------------------------------------------------------
__global__ __launch_bounds__(256) void norm_rows_kernel(
    const float* __restrict__ Wpos, const float* __restrict__ W1,
    const float* __restrict__ W2, const float* __restrict__ W3,
    float* __restrict__ ws) {
  int r = blockIdx.x * 4 + (threadIdx.x >> 6);
  int lane = threadIdx.x & 63;
  const float* src;
  float* dst;
  int C;
  if (r < 64)       { src = Wpos + r * 3;          dst = ws + OWNPOS + r * 3;          C = 3;   }
  else if (r < 192) { int rr = r - 64;  src = W1 + rr * 64;  dst = ws + OWN1 + rr * 64;  C = 64;  }
  else if (r < 320) { int rr = r - 192; src = W2 + rr * 256; dst = ws + OWN2 + rr * 256; C = 256; }
  else              { int rr = r - 320; src = W3 + rr * 256; dst = ws + OWN3 + rr * 256; C = 256; }
  float s = 0.f;
  for (int i = lane; i < C; i += 64) s += src[i];
#pragma unroll
  for (int off = 32; off > 0; off >>= 1) s += __shfl_xor(s, off);
  for (int i = lane; i < C; i += 64) dst[i] = src[i] / s;
}

// ---------------------------------------------------------------------------
// K1b: pack stacked [Wn ; D] (first C cols) into bf16 hi/lo, K doubled.
// ---------------------------------------------------------------------------
__global__ __launch_bounds__(256) void pack_w_kernel(
    const float* __restrict__ Wn, const float* __restrict__ Draw,
    int C, int ldw, unsigned short* __restrict__ dst) {
  int idx = blockIdx.x * 256 + threadIdx.x;
  if (idx >= 256 * C) return;
  int m = idx / C, c = idx % C;
  float x = (m < 128) ? Wn[m * ldw + c] : Draw[(m - 128) * ldw + c];
  *(unsigned int*)(dst + (size_t)(m * C + c) * 2) = packhl(x);
}

// ---------------------------------------------------------------------------
// K2: exact top-20 KNN (unchanged).
// ---------------------------------------------------------------------------
__global__ __launch_bounds__(256, 4) void knn_kernel(const float* __restrict__ pc,
                                                     int* __restrict__ idxout) {
  __shared__ float4 spt[N];
  __shared__ unsigned short sbuf[4][512];
  int tid = threadIdx.x;
  int b = blockIdx.y;
  const float* pcb = pc + b * N * 3;
  for (int i = tid; i < N; i += 256) {
    float x = pcb[i * 3 + 0], y = pcb[i * 3 + 1], z = pcb[i * 3 + 2];
    float xx = __fadd_rn(__fadd_rn(__fmul_rn(x, x), __fmul_rn(y, y)), __fmul_rn(z, z));
    spt[i] = make_float4(2.f * x, 2.f * y, 2.f * z, xx);
  }
  __syncthreads();
  int wv = tid >> 6, lane = tid & 63;
  int q = blockIdx.x * 4 + wv;
  float4 qp = spt[q];
  float qx = 0.5f * qp.x, qy = 0.5f * qp.y, qz = 0.5f * qp.z, qxx = qp.w;

  float dv[32];
  float lmax = -INFINITY;
#pragma unroll
  for (int i = 0; i < 32; ++i) {
    float4 m = spt[i * 64 + lane];
    float A = __fadd_rn(__fadd_rn(__fmul_rn(m.x, qx), __fmul_rn(m.y, qy)),
                        __fmul_rn(m.z, qz));
    float d = __fsub_rn(__fsub_rn(A, qxx), m.w);
    dv[i] = d;
    lmax = fmaxf(lmax, d);
  }
  unsigned u = __float_as_uint(lmax);
  u = u ^ ((u >> 31) ? 0xFFFFFFFFu : 0x80000000u);
  unsigned prefix = 0u;
#pragma unroll
  for (int bit = 31; bit >= 0; --bit) {
    unsigned test = prefix | (1u << bit);
    int cnt = (int)__popcll(__ballot(u >= test));
    if (cnt >= KNN) prefix = test;
  }
  float tval = __uint_as_float((prefix >> 31) ? (prefix ^ 0x80000000u) : ~prefix);

  int base = 0;
#pragma unroll
  for (int i = 0; i < 32; ++i) {
    bool s = dv[i] >= tval;
    unsigned long long mk = __ballot(s);
    if (s) {
      int pos = base + (int)__popcll(mk & ((1ull << lane) - 1ull));
      if (pos < 512) sbuf[wv][pos] = (unsigned short)(i * 64 + lane);
    }
    base += (int)__popcll(mk);
  }
  int S = base;

  auto distOf = [&](int m) -> float {
    float4 mp = spt[m];
    float A = __fadd_rn(__fadd_rn(__fmul_rn(mp.x, qx), __fmul_rn(mp.y, qy)),
                        __fmul_rn(mp.z, qz));
    return __fsub_rn(__fsub_rn(A, qxx), mp.w);
  };

  float cv = -INFINITY;
  int cm = 0x7fffffff;
  if (S <= 64) {
    if (lane < S) { cm = sbuf[wv][lane]; cv = distOf(cm); }
    wave_sort64(cv, cm, lane);
  } else if (S <= 512) {
    int pos = 0;
    while (pos < S) {
      if (lane >= KNN) {
        int t = pos + lane - KNN;
        if (t < S) { cm = sbuf[wv][t]; cv = distOf(cm); }
        else       { cm = 0x7fffffff;  cv = -INFINITY; }
      }
      wave_sort64(cv, cm, lane);
      pos += 64 - KNN;
    }
  } else {
    int pos = 0;
    while (pos < N) {
      if (lane >= KNN) {
        int t = pos + lane - KNN;
        if (t < N) { cm = t; cv = distOf(t); }
        else       { cm = 0x7fffffff; cv = -INFINITY; }
      }
      wave_sort64(cv, cm, lane);
      pos += 64 - KNN;
    }
  }
  if (lane < KNN) idxout[(b * N + q) * KNN + lane] = cm;
}

// ---------------------------------------------------------------------------
// K3: edge features -> pos layer (64ch) -> VN-LeakyReLU -> mean over k.
// ---------------------------------------------------------------------------
__global__ __launch_bounds__(256) void edge_pos_kernel(
    const float* __restrict__ pc, const int* __restrict__ knn,
    const float* __restrict__ Wn, const float* __restrict__ Dp,
    float* __restrict__ net0) {
  int tid = threadIdx.x;
  int og = blockIdx.x, nt = blockIdx.y, b = blockIdx.z;
  int n = nt * 256 + tid;
  const float* pcb = pc + b * N * 3;
  float cx = pcb[n * 3 + 0], cy = pcb[n * 3 + 1], cz = pcb[n * 3 + 2];

  float w[4][3], dw[4][3], ax[4], ay[4], az[4];
#pragma unroll
  for (int j = 0; j < 4; ++j) {
    int o = og * 4 + j;
    w[j][0] = Wn[o * 3 + 0]; w[j][1] = Wn[o * 3 + 1]; w[j][2] = Wn[o * 3 + 2];
    dw[j][0] = Dp[o * 3 + 0]; dw[j][1] = Dp[o * 3 + 1]; dw[j][2] = Dp[o * 3 + 2];
    ax[j] = 0.f; ay[j] = 0.f; az[j] = 0.f;
  }
  const int* kn = knn + (b * N + n) * KNN;
  for (int k = 0; k < KNN; ++k) {
    int m = kn[k];
    float nx = pcb[m * 3 + 0], ny = pcb[m * 3 + 1], nz = pcb[m * 3 + 2];
    float ex = nx - cx, ey = ny - cy, ez = nz - cz;
    float rx = ny * cz - nz * cy;
    float ry = nz * cx - nx * cz;
    float rz = nx * cy - ny * cx;
#pragma unroll
    for (int j = 0; j < 4; ++j) {
      float px = fmaf(w[j][0], ex, fmaf(w[j][1], cx, w[j][2] * rx));
      float py = fmaf(w[j][0], ey, fmaf(w[j][1], cy, w[j][2] * ry));
      float pz = fmaf(w[j][0], ez, fmaf(w[j][1], cz, w[j][2] * rz));
      float dx = fmaf(dw[j][0], ex, fmaf(dw[j][1], cx, dw[j][2] * rx));
      float dy = fmaf(dw[j][0], ey, fmaf(dw[j][1], cy, dw[j][2] * ry));
      float dz = fmaf(dw[j][0], ez, fmaf(dw[j][1], cz, dw[j][2] * rz));
      float dot = fmaf(px, dx, fmaf(py, dy, pz * dz));
      float dns = fmaf(dx, dx, fmaf(dy, dy, dz * dz));
      float f = (dot < 0.f) ? dot / (dns + 1e-6f) : 0.f;
      ax[j] += px - f * dx;
      ay[j] += py - f * dy;
      az[j] += pz - f * dz;
    }
  }
#pragma unroll
  for (int j = 0; j < 4; ++j) {
    int o = og * 4 + j;
    net0[((b * 64 + o) * 3 + 0) * N + n] = ax[j] * (1.f / 20.f);
    net0[((b * 64 + o) * 3 + 1) * N + n] = ay[j] * (1.f / 20.f);
    net0[((b * 64 + o) * 3 + 2) * N + n] = az[j] * (1.f / 20.f);
  }
}

// ---------------------------------------------------------------------------
// K3b: pack net0 fp32 -> Xp0 bf16 hi/lo, pixel layout p=(n>>4)*48+v*16+(n&15).
// ---------------------------------------------------------------------------
__global__ __launch_bounds__(256) void pack0_kernel(
    const float* __restrict__ net0, unsigned short* __restrict__ Xp0) {
  int g = blockIdx.x * 256 + threadIdx.x;  // B*N threads
  int b = g >> 11, n = g & 2047;
  int pbase = ((n >> 4) * 48) + (n & 15);
#pragma unroll
  for (int v = 0; v < 3; ++v) {
    unsigned short* dst = Xp0 + ((size_t)b * P + pbase + v * 16) * 128;
#pragma unroll 8
    for (int c = 0; c < 64; ++c) {
      float x = net0[((b * 64 + c) * 3 + v) * N + n];
      *(unsigned int*)(dst + 2 * c) = packhl(x);
    }
  }
}

// ---------------------------------------------------------------------------
// K5/K7: bias for pooled-concat half, summing the 8 pool shadow copies:
// bias[b][m][v] = sum_c row[m][C+c] * (sum_k ps[k][b][c][v]) / N
// ---------------------------------------------------------------------------
__global__ __launch_bounds__(256) void bias_kernel(
    const float* __restrict__ Wn, const float* __restrict__ Draw,
    const float* __restrict__ ps, float* __restrict__ bias) {
  int idx = blockIdx.x * 256 + threadIdx.x;  // B*256*3
  if (idx >= B * 256 * 3) return;
  int v = idx % 3;
  int m = (idx / 3) & 255;
  int b = idx / 768;
  const float* row = ((m < 128) ? (Wn + m * 256) : (Draw + (m - 128) * 256)) + 128;
  float s = 0.f;
  for (int c = 0; c < 128; ++c) {
    float x = 0.f;
    const float* pp = ps + (b * 128 + c) * 3 + v;
#pragma unroll
    for (int k = 0; k < 8; ++k) x += pp[k * 3072];
    s = fmaf(row[c], x, s);
  }
  bias[idx] = s * (1.f / 2048.f);
}

// ---------------------------------------------------------------------------
// K9: merge 8 out shadows -> d_out (mean over N).
// ---------------------------------------------------------------------------
__global__ __launch_bounds__(256) void out_merge_kernel(
    const float* __restrict__ outs, float* __restrict__ out) {
  int idx = blockIdx.x * 256 + threadIdx.x;  // 3072
  if (idx >= B * 384) return;
  float s = 0.f;
#pragma unroll
  for (int k = 0; k < 8; ++k) s += outs[k * 3072 + idx];
  out[idx] = s * (1.f / 2048.f);
}

// ---------------------------------------------------------------------------
// K4/K6/K8: MFMA VNT layer with LDS-staged epilogue (see round-6 notes).
// ---------------------------------------------------------------------------
template <int K2, bool HASPOOL, bool LAST>
__global__ __launch_bounds__(256, 4) void gemm_vnt_kernel(
    const unsigned short* __restrict__ Xp, const unsigned short* __restrict__ Wb,
    const float* __restrict__ bias, unsigned short* __restrict__ Xq,
    float* __restrict__ pool, float* __restrict__ outs) {
  constexpr int KS = K2 / 32;
  constexpr int LDR = K2 + 8;   // halves; X-tile row stride
  constexpr int LDO = 132;      // floats; out-tile row stride (16B-aligned rows)
  __shared__ __align__(16) char smem[48 * LDO * 4];  // 25344 B, dual-purpose
  unsigned short* xt = (unsigned short*)smem;
  float* ot = (float*)smem;
  __shared__ float sb[768];
  int tid = threadIdx.x;
  int bid = blockIdx.x;
  int b = bid >> 7;
  int nt = bid & 127;
  int p0 = nt * 48;

  // stage X tile [48][K2] -> LDS
  for (int ch = tid; ch < 48 * (K2 / 8); ch += 256) {
    int rp = ch / (K2 / 8), cc = ch % (K2 / 8);
    *(uint4*)(xt + rp * LDR + cc * 8) =
        *(const uint4*)(Xp + ((size_t)b * P + p0 + rp) * K2 + cc * 8);
  }
  if (HASPOOL) {
    for (int i = tid; i < 768; i += 256) sb[i] = bias[b * 768 + i];
  }
  __syncthreads();

  int w = tid >> 6, lane = tid & 63;
  int q = lane >> 4, cl = lane & 15;

  f32x4 acc[2][2][3] = {};  // [t][pd][v]
  const unsigned short* wbase = Wb + (size_t)cl * K2 + q * 8;

  // software-pipelined A (weights) from global
  bf16x8 acur[2][2], anxt[2][2];
#pragma unroll
  for (int t = 0; t < 2; ++t)
#pragma unroll
    for (int pd = 0; pd < 2; ++pd)
      acur[t][pd] = *(const bf16x8*)(wbase + (size_t)(32 * w + 16 * t + 128 * pd) * K2);

#pragma unroll
  for (int ks = 0; ks < KS; ++ks) {
    if (ks + 1 < KS) {
#pragma unroll
      for (int t = 0; t < 2; ++t)
#pragma unroll
        for (int pd = 0; pd < 2; ++pd)
          anxt[t][pd] = *(const bf16x8*)(wbase +
              (size_t)(32 * w + 16 * t + 128 * pd) * K2 + (ks + 1) * 32);
    }
    bf16x8 bb[3];
#pragma unroll
    for (int v = 0; v < 3; ++v)
      bb[v] = *(const bf16x8*)(xt + (v * 16 + cl) * LDR + ks * 32 + q * 8);
#pragma unroll
    for (int t = 0; t < 2; ++t)
#pragma unroll
      for (int pd = 0; pd < 2; ++pd)
#pragma unroll
        for (int v = 0; v < 3; ++v)
          acc[t][pd][v] = __builtin_amdgcn_mfma_f32_16x16x32_bf16(
              acur[t][pd], bb[v], acc[t][pd][v], 0, 0, 0);
#pragma unroll
    for (int t = 0; t < 2; ++t)
#pragma unroll
      for (int pd = 0; pd < 2; ++pd)
        acur[t][pd] = anxt[t][pd];
  }
  __syncthreads();  // X-tile dead; buffer becomes the fp32 out-tile

  // activation -> LDS out-tile [pixel(48)][o(128)], row stride LDO
#pragma unroll
  for (int t = 0; t < 2; ++t) {
    float res[3][4];
#pragma unroll
    for (int r = 0; r < 4; ++r) {
      int o = 32 * w + 16 * t + 4 * q + r;
      float pv[3], dv[3];
#pragma unroll
      for (int v = 0; v < 3; ++v) {
        pv[v] = acc[t][0][v][r] + (HASPOOL ? sb[o * 3 + v] : 0.f);
        dv[v] = acc[t][1][v][r] + (HASPOOL ? sb[(128 + o) * 3 + v] : 0.f);
      }
      float dot = fmaf(pv[0], dv[0], fmaf(pv[1], dv[1], pv[2] * dv[2]));
      float dns = fmaf(dv[0], dv[0], fmaf(dv[1], dv[1], dv[2] * dv[2]));
      float f = (dot < 0.f) ? dot / (dns + 1e-6f) : 0.f;
#pragma unroll
      for (int v = 0; v < 3; ++v) res[v][r] = pv[v] - f * dv[v];
    }
    int o0 = 32 * w + 16 * t + 4 * q;
#pragma unroll
    for (int v = 0; v < 3; ++v) {
      f32x4 rv = {res[v][0], res[v][1], res[v][2], res[v][3]};
      *(f32x4*)(ot + (v * 16 + cl) * LDO + o0) = rv;
    }
  }
  __syncthreads();

  // (a) pool sums: 16 pixels per (o,v), lane-dense coalesced atomics into
  //     shadow copy nt&7
  int shadow = (nt & 7) * 3072;
  for (int s = tid; s < 384; s += 256) {
    int o = s / 3, v = s % 3;
    float a2 = 0.f;
#pragma unroll
    for (int c = 0; c < 16; ++c) a2 += ot[(v * 16 + c) * LDO + o];
    if (LAST) atomicAdd(outs + shadow + b * 384 + s, a2);
    else      atomicAdd(pool + shadow + b * 384 + s, a2);
  }

  // (b) coalesced pack + store of activated output (not for last layer)
  if (!LAST) {
    for (int s = tid; s < 1536; s += 256) {
      int pix = s >> 5, c4 = s & 31;
      const float* src = ot + pix * LDO + c4 * 4;
      uint4 vv;
      vv.x = packhl(src[0]);
      vv.y = packhl(src[1]);
      vv.z = packhl(src[2]);
      vv.w = packhl(src[3]);
      *(uint4*)(Xq + ((size_t)b * P + p0 + pix) * 256 + c4 * 8) = vv;
    }
  }
}

// ---------------------------------------------------------------------------
// launch
// ---------------------------------------------------------------------------
extern "C" void kernel_launch(void* const* d_in, const int* in_sizes, int n_in,
                              void* d_out, int out_size, void* d_ws, size_t ws_size,
                              hipStream_t stream) {
  (void)in_sizes; (void)n_in; (void)out_size; (void)ws_size;
  const float* pc   = (const float*)d_in[0];
  const float* Wpos = (const float*)d_in[1];
  const float* Dpos = (const float*)d_in[2];
  const float* W1   = (const float*)d_in[3];
  const float* D1   = (const float*)d_in[4];
  const float* W2   = (const float*)d_in[5];
  const float* D2   = (const float*)d_in[6];
  const float* W3   = (const float*)d_in[7];
  const float* D3   = (const float*)d_in[8];
  float* out = (float*)d_out;
  float* ws  = (float*)d_ws;

  // zero pool/out shadows (contiguous 73728 floats)
  hipMemsetAsync(ws + OPS1, 0, 73728 * sizeof(float), stream);

  norm_rows_kernel<<<112, 256, 0, stream>>>(Wpos, W1, W2, W3, ws);
  pack_w_kernel<<<64, 256, 0, stream>>>(ws + OWN1, D1, 64, 64,
                                        (unsigned short*)(ws + OWB1));
  pack_w_kernel<<<128, 256, 0, stream>>>(ws + OWN2, D2, 128, 256,
                                         (unsigned short*)(ws + OWB2));
  pack_w_kernel<<<128, 256, 0, stream>>>(ws + OWN3, D3, 128, 256,
                                         (unsigned short*)(ws + OWB3));
  knn_kernel<<<dim3(N / 4, B), 256, 0, stream>>>(pc, (int*)(ws + OIDX));
  edge_pos_kernel<<<dim3(16, 8, 8), 256, 0, stream>>>(
      pc, (const int*)(ws + OIDX), ws + OWNPOS, Dpos, ws + ONET0);
  pack0_kernel<<<64, 256, 0, stream>>>(ws + ONET0, (unsigned short*)(ws + OXP0));
  // layer1: K2=128 -> Xp1 + ps1 shadows
  gemm_vnt_kernel<128, false, false><<<1024, 256, 0, stream>>>(
      (const unsigned short*)(ws + OXP0), (const unsigned short*)(ws + OWB1),
      nullptr, (unsigned short*)(ws + OXP1), ws + OPS1, nullptr);
  bias_kernel<<<24, 256, 0, stream>>>(ws + OWN2, D2, ws + OPS1, ws + OBIAS2);
  // layer2: -> Xp2 + ps2 shadows
  gemm_vnt_kernel<256, true, false><<<1024, 256, 0, stream>>>(
      (const unsigned short*)(ws + OXP1), (const unsigned short*)(ws + OWB2),
      ws + OBIAS2, (unsigned short*)(ws + OXP2), ws + OPS2, nullptr);
  bias_kernel<<<24, 256, 0, stream>>>(ws + OWN3, D3, ws + OPS2, ws + OBIAS3);
  // layer3: -> out shadows
  gemm_vnt_kernel<256, true, true><<<1024, 256, 0, stream>>>(
      (const unsigned short*)(ws + OXP2), (const unsigned short*)(ws + OWB3),
      ws + OBIAS3, nullptr, nullptr, ws + OOUTS);
  out_merge_kernel<<<12, 256, 0, stream>>>(ws + OOUTS, out);
}

// Round 7
// 235.031 us; speedup vs baseline: 1.8771x; 1.0775x over previous
//
#include <hip/hip_runtime.h>
#include <hip/hip_bf16.h>
#include <math.h>

// ---------------------------------------------------------------------------
// Problem constants
// ---------------------------------------------------------------------------
constexpr int B = 8;
constexpr int N = 2048;
constexpr int KNN = 20;
constexpr int H = 128;
constexpr int P = 3 * N;  // 6144 pixels per batch

// ws layout (float offsets)
constexpr int OWNPOS = 0;         // 64x3 normalized W_pos (pad 256)
constexpr int OWN2   = 8448;      // 128x256 normalized W2 fp32 (for bias)
constexpr int OWN3   = 41216;     // 128x256 normalized W3 fp32
constexpr int OPS1   = 73984;     // poolsum1 shadows [8][B][128][3] = 24576
constexpr int OPS2   = 98560;     // poolsum2 shadows = 24576
constexpr int OOUTS  = 123136;    // out shadows [8][B][384] = 24576
constexpr int OBIAS2 = 147712;    // bias2 [b][256][3] = 6144
constexpr int OBIAS3 = 153856;    // bias3 = 6144
constexpr int OWB1   = 160000;    // Wbig1 256x128 bf16 hi/lo (16384 f)
constexpr int OWB2   = 176384;    // Wbig2 256x256 bf16 hi/lo (32768 f)
constexpr int OWB3   = 209152;    // Wbig3 256x256 bf16 hi/lo (32768 f)
constexpr int OIDX   = 241920;    // knn idx: 8*2048*20 ints = 327680
constexpr int OXP0   = 569600;    // Xp0 bf16 [b][P][128] (3145728 f-equiv)
constexpr int OXP2   = 569600;    // Xp2 bf16 [b][P][256] (6291456) reuses Xp0
constexpr int OXP1   = 6861056;   // Xp1 bf16 [b][P][256] (6291456 f-equiv)
// max extent 13,152,512 floats ~= 52.6 MB (same as round 6)

constexpr int ZERO_BASE = OPS1;   // prep zeroes [OPS1, OPS1+73728)
constexpr int ZERO_CNT  = 73728;
constexpr int PREP_BLOCKS = 208;  // 832 waves

typedef __attribute__((ext_vector_type(8))) short bf16x8;
typedef __attribute__((ext_vector_type(4))) float f32x4;

__device__ __forceinline__ unsigned short f2bf(float x) {
  __hip_bfloat16 h = __float2bfloat16(x);
  return *(unsigned short*)&h;
}
__device__ __forceinline__ float bf2f(unsigned short u) {
  __hip_bfloat16 h;
  *(unsigned short*)&h = u;
  return __bfloat162float(h);
}
// pack x as (hi, lo) bf16 pair in one uint (hi at lower address)
__device__ __forceinline__ unsigned int packhl(float x) {
  unsigned short hi = f2bf(x);
  float lo = x - bf2f(hi);
  unsigned short ls = f2bf(lo);
  return (unsigned)hi | ((unsigned)ls << 16);
}

// ---------------------------------------------------------------------------
// Wave-wide bitonic sort of 64 (value,index) pairs, descending, tie->low idx.
// ---------------------------------------------------------------------------
__device__ __forceinline__ void wave_sort64(float& v, int& m, int lane) {
#pragma unroll
  for (int k = 2; k <= 64; k <<= 1) {
#pragma unroll
    for (int j = k >> 1; j > 0; j >>= 1) {
      float pv = __shfl_xor(v, j);
      int   pm = __shfl_xor(m, j);
      bool iam_lower   = (lane & j) == 0;
      bool dir_desc    = (lane & k) == 0;
      bool p_better    = (pv > v) || (pv == v && pm < m);
      bool want_better = (dir_desc == iam_lower);
      bool take        = (p_better == want_better);
      v = take ? pv : v;
      m = take ? pm : m;
    }
  }
}

// ---------------------------------------------------------------------------
// K1 (fused prep): zero pool/out shadows; normalize W rows (sum over the FULL
// row) and emit fp32 (where bias needs it) + bf16 hi/lo packed first-C cols;
// pack raw D rows.  One wave per row, 832 waves.
// ---------------------------------------------------------------------------
__global__ __launch_bounds__(256) void prep_kernel(
    const float* __restrict__ Wpos, const float* __restrict__ W1,
    const float* __restrict__ D1, const float* __restrict__ W2,
    const float* __restrict__ D2, const float* __restrict__ W3,
    const float* __restrict__ D3, float* __restrict__ ws) {
  for (int i = blockIdx.x * 256 + threadIdx.x; i < ZERO_CNT; i += PREP_BLOCKS * 256)
    ws[ZERO_BASE + i] = 0.f;

  int r = blockIdx.x * 4 + (threadIdx.x >> 6);
  int lane = threadIdx.x & 63;
  const float* src;
  float* fdst = nullptr;
  unsigned int* pdst = nullptr;
  int C, Cpack;
  bool norm = true;
  if (r < 64)       { src = Wpos + r * 3; fdst = ws + OWNPOS + r * 3; C = 3; Cpack = 0; }
  else if (r < 192) { int m = r - 64;  src = W1 + m * 64;  C = 64;  Cpack = 64;
                      pdst = (unsigned int*)(ws + OWB1) + m * 64; }
  else if (r < 320) { int m = r - 192; src = D1 + m * 64;  C = 64;  Cpack = 64; norm = false;
                      pdst = (unsigned int*)(ws + OWB1) + (m + 128) * 64; }
  else if (r < 448) { int m = r - 320; src = W2 + m * 256; C = 256; Cpack = 128;
                      fdst = ws + OWN2 + m * 256;
                      pdst = (unsigned int*)(ws + OWB2) + m * 128; }
  else if (r < 576) { int m = r - 448; src = D2 + m * 256; C = 256; Cpack = 128; norm = false;
                      pdst = (unsigned int*)(ws + OWB2) + (m + 128) * 128; }
  else if (r < 704) { int m = r - 576; src = W3 + m * 256; C = 256; Cpack = 128;
                      fdst = ws + OWN3 + m * 256;
                      pdst = (unsigned int*)(ws + OWB3) + m * 128; }
  else              { int m = r - 704; src = D3 + m * 256; C = 256; Cpack = 128; norm = false;
                      pdst = (unsigned int*)(ws + OWB3) + (m + 128) * 128; }

  float s = 1.f;
  if (norm) {
    float a = 0.f;
    for (int i = lane; i < C; i += 64) a += src[i];
#pragma unroll
    for (int off = 32; off > 0; off >>= 1) a += __shfl_xor(a, off);
    s = a;
  }
  for (int i = lane; i < C; i += 64) {
    float val = src[i] / s;  // exact when s==1
    if (fdst) fdst[i] = val;
    if (pdst && i < Cpack) pdst[i] = packhl(val);
  }
}

// ---------------------------------------------------------------------------
// K2: exact top-20 KNN (unchanged).
// ---------------------------------------------------------------------------
__global__ __launch_bounds__(256, 4) void knn_kernel(const float* __restrict__ pc,
                                                     int* __restrict__ idxout) {
  __shared__ float4 spt[N];
  __shared__ unsigned short sbuf[4][512];
  int tid = threadIdx.x;
  int b = blockIdx.y;
  const float* pcb = pc + b * N * 3;
  for (int i = tid; i < N; i += 256) {
    float x = pcb[i * 3 + 0], y = pcb[i * 3 + 1], z = pcb[i * 3 + 2];
    float xx = __fadd_rn(__fadd_rn(__fmul_rn(x, x), __fmul_rn(y, y)), __fmul_rn(z, z));
    spt[i] = make_float4(2.f * x, 2.f * y, 2.f * z, xx);
  }
  __syncthreads();
  int wv = tid >> 6, lane = tid & 63;
  int q = blockIdx.x * 4 + wv;
  float4 qp = spt[q];
  float qx = 0.5f * qp.x, qy = 0.5f * qp.y, qz = 0.5f * qp.z, qxx = qp.w;

  float dv[32];
  float lmax = -INFINITY;
#pragma unroll
  for (int i = 0; i < 32; ++i) {
    float4 m = spt[i * 64 + lane];
    float A = __fadd_rn(__fadd_rn(__fmul_rn(m.x, qx), __fmul_rn(m.y, qy)),
                        __fmul_rn(m.z, qz));
    float d = __fsub_rn(__fsub_rn(A, qxx), m.w);
    dv[i] = d;
    lmax = fmaxf(lmax, d);
  }
  unsigned u = __float_as_uint(lmax);
  u = u ^ ((u >> 31) ? 0xFFFFFFFFu : 0x80000000u);
  unsigned prefix = 0u;
#pragma unroll
  for (int bit = 31; bit >= 0; --bit) {
    unsigned test = prefix | (1u << bit);
    int cnt = (int)__popcll(__ballot(u >= test));
    if (cnt >= KNN) prefix = test;
  }
  float tval = __uint_as_float((prefix >> 31) ? (prefix ^ 0x80000000u) : ~prefix);

  int base = 0;
#pragma unroll
  for (int i = 0; i < 32; ++i) {
    bool s = dv[i] >= tval;
    unsigned long long mk = __ballot(s);
    if (s) {
      int pos = base + (int)__popcll(mk & ((1ull << lane) - 1ull));
      if (pos < 512) sbuf[wv][pos] = (unsigned short)(i * 64 + lane);
    }
    base += (int)__popcll(mk);
  }
  int S = base;

  auto distOf = [&](int m) -> float {
    float4 mp = spt[m];
    float A = __fadd_rn(__fadd_rn(__fmul_rn(mp.x, qx), __fmul_rn(mp.y, qy)),
                        __fmul_rn(mp.z, qz));
    return __fsub_rn(__fsub_rn(A, qxx), mp.w);
  };

  float cv = -INFINITY;
  int cm = 0x7fffffff;
  if (S <= 64) {
    if (lane < S) { cm = sbuf[wv][lane]; cv = distOf(cm); }
    wave_sort64(cv, cm, lane);
  } else if (S <= 512) {
    int pos = 0;
    while (pos < S) {
      if (lane >= KNN) {
        int t = pos + lane - KNN;
        if (t < S) { cm = sbuf[wv][t]; cv = distOf(cm); }
        else       { cm = 0x7fffffff;  cv = -INFINITY; }
      }
      wave_sort64(cv, cm, lane);
      pos += 64 - KNN;
    }
  } else {
    int pos = 0;
    while (pos < N) {
      if (lane >= KNN) {
        int t = pos + lane - KNN;
        if (t < N) { cm = t; cv = distOf(t); }
        else       { cm = 0x7fffffff; cv = -INFINITY; }
      }
      wave_sort64(cv, cm, lane);
      pos += 64 - KNN;
    }
  }
  if (lane < KNN) idxout[(b * N + q) * KNN + lane] = cm;
}

// ---------------------------------------------------------------------------
// K3: edge features -> pos layer (64ch) -> VN-LeakyReLU -> mean over k ->
// DIRECT bf16 hi/lo pack into Xp0 (pixel layout p=(n>>4)*48+v*16+(n&15)).
// One uint4 store per (thread, v): 4 channels x (hi,lo).  Wave-store =
// 4 contiguous 256B segments (16 lanes x 16B each).  net0/pack0 eliminated.
// ---------------------------------------------------------------------------
__global__ __launch_bounds__(256) void edge_pos_kernel(
    const float* __restrict__ pc, const int* __restrict__ knn,
    const float* __restrict__ Wn, const float* __restrict__ Dp,
    unsigned short* __restrict__ Xp0) {
  int tid = threadIdx.x;
  int og = blockIdx.x, nt = blockIdx.y, b = blockIdx.z;
  int n = nt * 256 + tid;
  const float* pcb = pc + b * N * 3;
  float cx = pcb[n * 3 + 0], cy = pcb[n * 3 + 1], cz = pcb[n * 3 + 2];

  float w[4][3], dw[4][3], acc[3][4];
#pragma unroll
  for (int j = 0; j < 4; ++j) {
    int o = og * 4 + j;
    w[j][0] = Wn[o * 3 + 0]; w[j][1] = Wn[o * 3 + 1]; w[j][2] = Wn[o * 3 + 2];
    dw[j][0] = Dp[o * 3 + 0]; dw[j][1] = Dp[o * 3 + 1]; dw[j][2] = Dp[o * 3 + 2];
    acc[0][j] = 0.f; acc[1][j] = 0.f; acc[2][j] = 0.f;
  }
  const int* kn = knn + (b * N + n) * KNN;
  for (int k = 0; k < KNN; ++k) {
    int m = kn[k];
    float nx = pcb[m * 3 + 0], ny = pcb[m * 3 + 1], nz = pcb[m * 3 + 2];
    float ex = nx - cx, ey = ny - cy, ez = nz - cz;
    float rx = ny * cz - nz * cy;
    float ry = nz * cx - nx * cz;
    float rz = nx * cy - ny * cx;
#pragma unroll
    for (int j = 0; j < 4; ++j) {
      float px = fmaf(w[j][0], ex, fmaf(w[j][1], cx, w[j][2] * rx));
      float py = fmaf(w[j][0], ey, fmaf(w[j][1], cy, w[j][2] * ry));
      float pz = fmaf(w[j][0], ez, fmaf(w[j][1], cz, w[j][2] * rz));
      float dx = fmaf(dw[j][0], ex, fmaf(dw[j][1], cx, dw[j][2] * rx));
      float dy = fmaf(dw[j][0], ey, fmaf(dw[j][1], cy, dw[j][2] * ry));
      float dz = fmaf(dw[j][0], ez, fmaf(dw[j][1], cz, dw[j][2] * rz));
      float dot = fmaf(px, dx, fmaf(py, dy, pz * dz));
      float dns = fmaf(dx, dx, fmaf(dy, dy, dz * dz));
      float f = (dot < 0.f) ? dot / (dns + 1e-6f) : 0.f;
      acc[0][j] += px - f * dx;
      acc[1][j] += py - f * dy;
      acc[2][j] += pz - f * dz;
    }
  }
  int pbase = ((n >> 4) * 48) + (n & 15);
#pragma unroll
  for (int v = 0; v < 3; ++v) {
    uint4 vv;
    vv.x = packhl(acc[v][0] * (1.f / 20.f));
    vv.y = packhl(acc[v][1] * (1.f / 20.f));
    vv.z = packhl(acc[v][2] * (1.f / 20.f));
    vv.w = packhl(acc[v][3] * (1.f / 20.f));
    *(uint4*)(Xp0 + ((size_t)b * P + pbase + v * 16) * 128 + og * 8) = vv;
  }
}

// ---------------------------------------------------------------------------
// K5/K7: bias for pooled-concat half, summing the 8 pool shadow copies.
// ---------------------------------------------------------------------------
__global__ __launch_bounds__(256) void bias_kernel(
    const float* __restrict__ Wn, const float* __restrict__ Draw,
    const float* __restrict__ ps, float* __restrict__ bias) {
  int idx = blockIdx.x * 256 + threadIdx.x;  // B*256*3
  if (idx >= B * 256 * 3) return;
  int v = idx % 3;
  int m = (idx / 3) & 255;
  int b = idx / 768;
  const float* row = ((m < 128) ? (Wn + m * 256) : (Draw + (m - 128) * 256)) + 128;
  float s = 0.f;
  for (int c = 0; c < 128; ++c) {
    float x = 0.f;
    const float* pp = ps + (b * 128 + c) * 3 + v;
#pragma unroll
    for (int k = 0; k < 8; ++k) x += pp[k * 3072];
    s = fmaf(row[c], x, s);
  }
  bias[idx] = s * (1.f / 2048.f);
}

// ---------------------------------------------------------------------------
// K9: merge 8 out shadows -> d_out (mean over N).
// ---------------------------------------------------------------------------
__global__ __launch_bounds__(256) void out_merge_kernel(
    const float* __restrict__ outs, float* __restrict__ out) {
  int idx = blockIdx.x * 256 + threadIdx.x;  // 3072
  if (idx >= B * 384) return;
  float s = 0.f;
#pragma unroll
  for (int k = 0; k < 8; ++k) s += outs[k * 3072 + idx];
  out[idx] = s * (1.f / 2048.f);
}

// ---------------------------------------------------------------------------
// K4/K6/K8: MFMA VNT layer with LDS-staged epilogue.
// ---------------------------------------------------------------------------
template <int K2, bool HASPOOL, bool LAST>
__global__ __launch_bounds__(256, 4) void gemm_vnt_kernel(
    const unsigned short* __restrict__ Xp, const unsigned short* __restrict__ Wb,
    const float* __restrict__ bias, unsigned short* __restrict__ Xq,
    float* __restrict__ pool, float* __restrict__ outs) {
  constexpr int KS = K2 / 32;
  constexpr int LDR = K2 + 8;   // halves; X-tile row stride
  constexpr int LDO = 132;      // floats; out-tile row stride
  __shared__ __align__(16) char smem[48 * LDO * 4];  // 25344 B, dual-purpose
  unsigned short* xt = (unsigned short*)smem;
  float* ot = (float*)smem;
  __shared__ float sb[768];
  int tid = threadIdx.x;
  int bid = blockIdx.x;
  int b = bid >> 7;
  int nt = bid & 127;
  int p0 = nt * 48;

  for (int ch = tid; ch < 48 * (K2 / 8); ch += 256) {
    int rp = ch / (K2 / 8), cc = ch % (K2 / 8);
    *(uint4*)(xt + rp * LDR + cc * 8) =
        *(const uint4*)(Xp + ((size_t)b * P + p0 + rp) * K2 + cc * 8);
  }
  if (HASPOOL) {
    for (int i = tid; i < 768; i += 256) sb[i] = bias[b * 768 + i];
  }
  __syncthreads();

  int w = tid >> 6, lane = tid & 63;
  int q = lane >> 4, cl = lane & 15;

  f32x4 acc[2][2][3] = {};  // [t][pd][v]
  const unsigned short* wbase = Wb + (size_t)cl * K2 + q * 8;

  bf16x8 acur[2][2], anxt[2][2];
#pragma unroll
  for (int t = 0; t < 2; ++t)
#pragma unroll
    for (int pd = 0; pd < 2; ++pd)
      acur[t][pd] = *(const bf16x8*)(wbase + (size_t)(32 * w + 16 * t + 128 * pd) * K2);

#pragma unroll
  for (int ks = 0; ks < KS; ++ks) {
    if (ks + 1 < KS) {
#pragma unroll
      for (int t = 0; t < 2; ++t)
#pragma unroll
        for (int pd = 0; pd < 2; ++pd)
          anxt[t][pd] = *(const bf16x8*)(wbase +
              (size_t)(32 * w + 16 * t + 128 * pd) * K2 + (ks + 1) * 32);
    }
    bf16x8 bb[3];
#pragma unroll
    for (int v = 0; v < 3; ++v)
      bb[v] = *(const bf16x8*)(xt + (v * 16 + cl) * LDR + ks * 32 + q * 8);
#pragma unroll
    for (int t = 0; t < 2; ++t)
#pragma unroll
      for (int pd = 0; pd < 2; ++pd)
#pragma unroll
        for (int v = 0; v < 3; ++v)
          acc[t][pd][v] = __builtin_amdgcn_mfma_f32_16x16x32_bf16(
              acur[t][pd], bb[v], acc[t][pd][v], 0, 0, 0);
#pragma unroll
    for (int t = 0; t < 2; ++t)
#pragma unroll
      for (int pd = 0; pd < 2; ++pd)
        acur[t][pd] = anxt[t][pd];
  }
  __syncthreads();  // X-tile dead; buffer becomes the fp32 out-tile

#pragma unroll
  for (int t = 0; t < 2; ++t) {
    float res[3][4];
#pragma unroll
    for (int r = 0; r < 4; ++r) {
      int o = 32 * w + 16 * t + 4 * q + r;
      float pv[3], dv[3];
#pragma unroll
      for (int v = 0; v < 3; ++v) {
        pv[v] = acc[t][0][v][r] + (HASPOOL ? sb[o * 3 + v] : 0.f);
        dv[v] = acc[t][1][v][r] + (HASPOOL ? sb[(128 + o) * 3 + v] : 0.f);
      }
      float dot = fmaf(pv[0], dv[0], fmaf(pv[1], dv[1], pv[2] * dv[2]));
      float dns = fmaf(dv[0], dv[0], fmaf(dv[1], dv[1], dv[2] * dv[2]));
      float f = (dot < 0.f) ? dot / (dns + 1e-6f) : 0.f;
#pragma unroll
      for (int v = 0; v < 3; ++v) res[v][r] = pv[v] - f * dv[v];
    }
    int o0 = 32 * w + 16 * t + 4 * q;
#pragma unroll
    for (int v = 0; v < 3; ++v) {
      f32x4 rv = {res[v][0], res[v][1], res[v][2], res[v][3]};
      *(f32x4*)(ot + (v * 16 + cl) * LDO + o0) = rv;
    }
  }
  __syncthreads();

  int shadow = (nt & 7) * 3072;
  for (int s = tid; s < 384; s += 256) {
    int o = s / 3, v = s % 3;
    float a2 = 0.f;
#pragma unroll
    for (int c = 0; c < 16; ++c) a2 += ot[(v * 16 + c) * LDO + o];
    if (LAST) atomicAdd(outs + shadow + b * 384 + s, a2);
    else      atomicAdd(pool + shadow + b * 384 + s, a2);
  }

  if (!LAST) {
    for (int s = tid; s < 1536; s += 256) {
      int pix = s >> 5, c4 = s & 31;
      const float* src = ot + pix * LDO + c4 * 4;
      uint4 vv;
      vv.x = packhl(src[0]);
      vv.y = packhl(src[1]);
      vv.z = packhl(src[2]);
      vv.w = packhl(src[3]);
      *(uint4*)(Xq + ((size_t)b * P + p0 + pix) * 256 + c4 * 8) = vv;
    }
  }
}

// ---------------------------------------------------------------------------
// launch
// ---------------------------------------------------------------------------
extern "C" void kernel_launch(void* const* d_in, const int* in_sizes, int n_in,
                              void* d_out, int out_size, void* d_ws, size_t ws_size,
                              hipStream_t stream) {
  (void)in_sizes; (void)n_in; (void)out_size; (void)ws_size;
  const float* pc   = (const float*)d_in[0];
  const float* Wpos = (const float*)d_in[1];
  const float* Dpos = (const float*)d_in[2];
  const float* W1   = (const float*)d_in[3];
  const float* D1   = (const float*)d_in[4];
  const float* W2   = (const float*)d_in[5];
  const float* D2   = (const float*)d_in[6];
  const float* W3   = (const float*)d_in[7];
  const float* D3   = (const float*)d_in[8];
  float* out = (float*)d_out;
  float* ws  = (float*)d_ws;

  prep_kernel<<<PREP_BLOCKS, 256, 0, stream>>>(Wpos, W1, D1, W2, D2, W3, D3, ws);
  knn_kernel<<<dim3(N / 4, B), 256, 0, stream>>>(pc, (int*)(ws + OIDX));
  edge_pos_kernel<<<dim3(16, 8, 8), 256, 0, stream>>>(
      pc, (const int*)(ws + OIDX), ws + OWNPOS, Dpos,
      (unsigned short*)(ws + OXP0));
  // layer1: K2=128 -> Xp1 + ps1 shadows
  gemm_vnt_kernel<128, false, false><<<1024, 256, 0, stream>>>(
      (const unsigned short*)(ws + OXP0), (const unsigned short*)(ws + OWB1),
      nullptr, (unsigned short*)(ws + OXP1), ws + OPS1, nullptr);
  bias_kernel<<<24, 256, 0, stream>>>(ws + OWN2, D2, ws + OPS1, ws + OBIAS2);
  // layer2: -> Xp2 (reuses Xp0 region) + ps2 shadows
  gemm_vnt_kernel<256, true, false><<<1024, 256, 0, stream>>>(
      (const unsigned short*)(ws + OXP1), (const unsigned short*)(ws + OWB2),
      ws + OBIAS2, (unsigned short*)(ws + OXP2), ws + OPS2, nullptr);
  bias_kernel<<<24, 256, 0, stream>>>(ws + OWN3, D3, ws + OPS2, ws + OBIAS3);
  // layer3: -> out shadows
  gemm_vnt_kernel<256, true, true><<<1024, 256, 0, stream>>>(
      (const unsigned short*)(ws + OXP2), (const unsigned short*)(ws + OWB3),
      ws + OBIAS3, nullptr, nullptr, ws + OOUTS);
  out_merge_kernel<<<12, 256, 0, stream>>>(ws + OOUTS, out);
}

// Round 8
// 216.964 us; speedup vs baseline: 2.0334x; 1.0833x over previous
//
#include <hip/hip_runtime.h>
#include <hip/hip_bf16.h>
#include <math.h>

// ---------------------------------------------------------------------------
// Problem constants
// ---------------------------------------------------------------------------
constexpr int B = 8;
constexpr int N = 2048;
constexpr int KNN = 20;
constexpr int H = 128;
constexpr int P = 3 * N;  // 6144 pixels per batch

// ws layout (float offsets)
constexpr int OWNPOS = 0;         // 64x3 normalized W_pos (pad 256)
constexpr int OWT2   = 8448;      // W2/D2 second-half TRANSPOSED [c<128][m<256] (32768)
constexpr int OWT3   = 41216;     // W3/D3 second-half transposed (32768)
constexpr int OPS1   = 73984;     // poolsum1 shadows [8][B][128][3] = 24576
constexpr int OPS2   = 98560;     // poolsum2 shadows = 24576
constexpr int OOUTS  = 123136;    // out shadows [8][B][384] = 24576
constexpr int OWB1   = 160000;    // Wbig1 256x128 bf16 hi/lo (16384 f)
constexpr int OWB2   = 176384;    // Wbig2 256x256 bf16 hi/lo (32768 f)
constexpr int OWB3   = 209152;    // Wbig3 256x256 bf16 hi/lo (32768 f)
constexpr int OIDX   = 241920;    // knn idx: 8*2048*20 ints = 327680
constexpr int OXP0   = 569600;    // Xp0 bf16 [b][P][128] (3145728 f-equiv)
constexpr int OXP2   = 569600;    // Xp2 bf16 [b][P][256] reuses Xp0 region
constexpr int OXP1   = 6861056;   // Xp1 bf16 [b][P][256] (6291456 f-equiv)
// max extent 13,152,512 floats ~= 52.6 MB

constexpr int ZERO_BASE = OPS1;   // prep zeroes [OPS1, OPS1+73728) = ps1+ps2+outs
constexpr int ZERO_CNT  = 73728;
constexpr int PREP_BLOCKS = 208;  // 832 waves = 832 rows

typedef __attribute__((ext_vector_type(8))) short bf16x8;
typedef __attribute__((ext_vector_type(4))) float f32x4;

__device__ __forceinline__ unsigned short f2bf(float x) {
  __hip_bfloat16 h = __float2bfloat16(x);
  return *(unsigned short*)&h;
}
__device__ __forceinline__ float bf2f(unsigned short u) {
  __hip_bfloat16 h;
  *(unsigned short*)&h = u;
  return __bfloat162float(h);
}
// pack x as (hi, lo) bf16 pair in one uint (hi at lower address)
__device__ __forceinline__ unsigned int packhl(float x) {
  unsigned short hi = f2bf(x);
  float lo = x - bf2f(hi);
  unsigned short ls = f2bf(lo);
  return (unsigned)hi | ((unsigned)ls << 16);
}

// ---------------------------------------------------------------------------
// Wave-wide bitonic sort of 64 (value,index) pairs, descending, tie->low idx.
// ---------------------------------------------------------------------------
__device__ __forceinline__ void wave_sort64(float& v, int& m, int lane) {
#pragma unroll
  for (int k = 2; k <= 64; k <<= 1) {
#pragma unroll
    for (int j = k >> 1; j > 0; j >>= 1) {
      float pv = __shfl_xor(v, j);
      int   pm = __shfl_xor(m, j);
      bool iam_lower   = (lane & j) == 0;
      bool dir_desc    = (lane & k) == 0;
      bool p_better    = (pv > v) || (pv == v && pm < m);
      bool want_better = (dir_desc == iam_lower);
      bool take        = (p_better == want_better);
      v = take ? pv : v;
      m = take ? pm : m;
    }
  }
}

// ---------------------------------------------------------------------------
// K1 (fused prep): zero shadows; normalize W rows; emit bf16 hi/lo packed
// first-C cols (stacked [Wn;D]); emit fp32 TRANSPOSED second-half cols for
// the in-gemm bias prologue.  One wave per row, 832 rows.
// ---------------------------------------------------------------------------
__global__ __launch_bounds__(256) void prep_kernel(
    const float* __restrict__ Wpos, const float* __restrict__ W1,
    const float* __restrict__ D1, const float* __restrict__ W2,
    const float* __restrict__ D2, const float* __restrict__ W3,
    const float* __restrict__ D3, float* __restrict__ ws) {
  for (int i = blockIdx.x * 256 + threadIdx.x; i < ZERO_CNT; i += PREP_BLOCKS * 256)
    ws[ZERO_BASE + i] = 0.f;

  int r = blockIdx.x * 4 + (threadIdx.x >> 6);
  int lane = threadIdx.x & 63;
  const float* src;
  float* fdst = nullptr;        // fp32 dest (Wpos only)
  float* tdst = nullptr;        // transposed second-half dest, column stride 256
  unsigned int* pdst = nullptr; // packed bf16 hi/lo dest
  int C, Cpack;
  bool norm = true;
  if (r < 64)       { src = Wpos + r * 3; fdst = ws + OWNPOS + r * 3; C = 3; Cpack = 0; }
  else if (r < 192) { int m = r - 64;  src = W1 + m * 64;  C = 64;  Cpack = 64;
                      pdst = (unsigned int*)(ws + OWB1) + m * 64; }
  else if (r < 320) { int m = r - 192; src = D1 + m * 64;  C = 64;  Cpack = 64; norm = false;
                      pdst = (unsigned int*)(ws + OWB1) + (m + 128) * 64; }
  else if (r < 448) { int m = r - 320; src = W2 + m * 256; C = 256; Cpack = 128;
                      pdst = (unsigned int*)(ws + OWB2) + m * 128;
                      tdst = ws + OWT2 + m; }
  else if (r < 576) { int m = r - 448; src = D2 + m * 256; C = 256; Cpack = 128; norm = false;
                      pdst = (unsigned int*)(ws + OWB2) + (m + 128) * 128;
                      tdst = ws + OWT2 + 128 + m; }
  else if (r < 704) { int m = r - 576; src = W3 + m * 256; C = 256; Cpack = 128;
                      pdst = (unsigned int*)(ws + OWB3) + m * 128;
                      tdst = ws + OWT3 + m; }
  else              { int m = r - 704; src = D3 + m * 256; C = 256; Cpack = 128; norm = false;
                      pdst = (unsigned int*)(ws + OWB3) + (m + 128) * 128;
                      tdst = ws + OWT3 + 128 + m; }

  float s = 1.f;
  if (norm) {
    float a = 0.f;
    for (int i = lane; i < C; i += 64) a += src[i];
#pragma unroll
    for (int off = 32; off > 0; off >>= 1) a += __shfl_xor(a, off);
    s = a;
  }
  for (int i = lane; i < C; i += 64) {
    float val = src[i] / s;  // exact when s==1
    if (fdst) fdst[i] = val;
    if (pdst && i < Cpack) pdst[i] = packhl(val);
    if (tdst && i >= 128) tdst[(i - 128) * 256] = val;
  }
}

// ---------------------------------------------------------------------------
// K2: exact top-20 KNN.  Threshold = 20th-largest lane-max via value-only
// bitonic sort (21 stages, pure VALU — replaces 32 serial SALU ballots).
// ---------------------------------------------------------------------------
__global__ __launch_bounds__(256, 4) void knn_kernel(const float* __restrict__ pc,
                                                     int* __restrict__ idxout) {
  __shared__ float4 spt[N];
  __shared__ unsigned short sbuf[4][512];
  int tid = threadIdx.x;
  int b = blockIdx.y;
  const float* pcb = pc + b * N * 3;
  for (int i = tid; i < N; i += 256) {
    float x = pcb[i * 3 + 0], y = pcb[i * 3 + 1], z = pcb[i * 3 + 2];
    float xx = __fadd_rn(__fadd_rn(__fmul_rn(x, x), __fmul_rn(y, y)), __fmul_rn(z, z));
    spt[i] = make_float4(2.f * x, 2.f * y, 2.f * z, xx);
  }
  __syncthreads();
  int wv = tid >> 6, lane = tid & 63;
  int q = blockIdx.x * 4 + wv;
  float4 qp = spt[q];
  float qx = 0.5f * qp.x, qy = 0.5f * qp.y, qz = 0.5f * qp.z, qxx = qp.w;

  float dv[32];
  float lmax = -INFINITY;
#pragma unroll
  for (int i = 0; i < 32; ++i) {
    float4 m = spt[i * 64 + lane];
    float A = __fadd_rn(__fadd_rn(__fmul_rn(m.x, qx), __fmul_rn(m.y, qy)),
                        __fmul_rn(m.z, qz));
    float d = __fsub_rn(__fsub_rn(A, qxx), m.w);
    dv[i] = d;
    lmax = fmaxf(lmax, d);
  }

  // value-only bitonic sort (descending) of the 64 lane-maxes; take #19
  float sv = lmax;
#pragma unroll
  for (int k = 2; k <= 64; k <<= 1) {
#pragma unroll
    for (int j = k >> 1; j > 0; j >>= 1) {
      float pv = __shfl_xor(sv, j);
      bool keep_max = ((lane & k) == 0) == ((lane & j) == 0);
      sv = keep_max ? fmaxf(sv, pv) : fminf(sv, pv);
    }
  }
  float tval = __shfl(sv, 19);  // 20th-largest lane-max <= V20 (provable)

  int base = 0;
#pragma unroll
  for (int i = 0; i < 32; ++i) {
    bool s = dv[i] >= tval;
    unsigned long long mk = __ballot(s);
    if (s) {
      int pos = base + (int)__popcll(mk & ((1ull << lane) - 1ull));
      if (pos < 512) sbuf[wv][pos] = (unsigned short)(i * 64 + lane);
    }
    base += (int)__popcll(mk);
  }
  int S = base;

  auto distOf = [&](int m) -> float {
    float4 mp = spt[m];
    float A = __fadd_rn(__fadd_rn(__fmul_rn(mp.x, qx), __fmul_rn(mp.y, qy)),
                        __fmul_rn(mp.z, qz));
    return __fsub_rn(__fsub_rn(A, qxx), mp.w);
  };

  float cv = -INFINITY;
  int cm = 0x7fffffff;
  if (S <= 64) {
    if (lane < S) { cm = sbuf[wv][lane]; cv = distOf(cm); }
    wave_sort64(cv, cm, lane);
  } else if (S <= 512) {
    int pos = 0;
    while (pos < S) {
      if (lane >= KNN) {
        int t = pos + lane - KNN;
        if (t < S) { cm = sbuf[wv][t]; cv = distOf(cm); }
        else       { cm = 0x7fffffff;  cv = -INFINITY; }
      }
      wave_sort64(cv, cm, lane);
      pos += 64 - KNN;
    }
  } else {
    int pos = 0;
    while (pos < N) {
      if (lane >= KNN) {
        int t = pos + lane - KNN;
        if (t < N) { cm = t; cv = distOf(t); }
        else       { cm = 0x7fffffff; cv = -INFINITY; }
      }
      wave_sort64(cv, cm, lane);
      pos += 64 - KNN;
    }
  }
  if (lane < KNN) idxout[(b * N + q) * KNN + lane] = cm;
}

// ---------------------------------------------------------------------------
// K3: edge features -> pos layer (64ch) -> VN-LeakyReLU -> mean over k ->
// direct bf16 hi/lo pack into Xp0.  Point cloud staged in LDS (coalesced
// 24KB copy); neighbor gathers are LDS reads, not scattered L2.
// ---------------------------------------------------------------------------
__global__ __launch_bounds__(256) void edge_pos_kernel(
    const float* __restrict__ pc, const int* __restrict__ knn,
    const float* __restrict__ Wn, const float* __restrict__ Dp,
    unsigned short* __restrict__ Xp0) {
  __shared__ float sp[N * 3];  // 24 KB
  int tid = threadIdx.x;
  int og = blockIdx.x, nt = blockIdx.y, b = blockIdx.z;
  const float* pcb = pc + (size_t)b * N * 3;
  for (int i = tid; i < N * 3; i += 256) sp[i] = pcb[i];
  __syncthreads();

  int n = nt * 256 + tid;
  float cx = sp[n * 3 + 0], cy = sp[n * 3 + 1], cz = sp[n * 3 + 2];

  float w[4][3], dw[4][3], acc[3][4];
#pragma unroll
  for (int j = 0; j < 4; ++j) {
    int o = og * 4 + j;
    w[j][0] = Wn[o * 3 + 0]; w[j][1] = Wn[o * 3 + 1]; w[j][2] = Wn[o * 3 + 2];
    dw[j][0] = Dp[o * 3 + 0]; dw[j][1] = Dp[o * 3 + 1]; dw[j][2] = Dp[o * 3 + 2];
    acc[0][j] = 0.f; acc[1][j] = 0.f; acc[2][j] = 0.f;
  }
  // neighbor indices: 5 aligned int4 loads (n*80B is 16B-aligned)
  const int4* kn4 = (const int4*)(knn + ((size_t)b * N + n) * KNN);
  int kidx[20];
#pragma unroll
  for (int t = 0; t < 5; ++t) {
    int4 kv = kn4[t];
    kidx[t * 4 + 0] = kv.x; kidx[t * 4 + 1] = kv.y;
    kidx[t * 4 + 2] = kv.z; kidx[t * 4 + 3] = kv.w;
  }
#pragma unroll 4
  for (int k = 0; k < KNN; ++k) {
    int m = kidx[k];
    float nx = sp[m * 3 + 0], ny = sp[m * 3 + 1], nz = sp[m * 3 + 2];
    float ex = nx - cx, ey = ny - cy, ez = nz - cz;
    float rx = ny * cz - nz * cy;
    float ry = nz * cx - nx * cz;
    float rz = nx * cy - ny * cx;
#pragma unroll
    for (int j = 0; j < 4; ++j) {
      float px = fmaf(w[j][0], ex, fmaf(w[j][1], cx, w[j][2] * rx));
      float py = fmaf(w[j][0], ey, fmaf(w[j][1], cy, w[j][2] * ry));
      float pz = fmaf(w[j][0], ez, fmaf(w[j][1], cz, w[j][2] * rz));
      float dx = fmaf(dw[j][0], ex, fmaf(dw[j][1], cx, dw[j][2] * rx));
      float dy = fmaf(dw[j][0], ey, fmaf(dw[j][1], cy, dw[j][2] * ry));
      float dz = fmaf(dw[j][0], ez, fmaf(dw[j][1], cz, dw[j][2] * rz));
      float dot = fmaf(px, dx, fmaf(py, dy, pz * dz));
      float dns = fmaf(dx, dx, fmaf(dy, dy, dz * dz));
      float f = (dot < 0.f) ? dot / (dns + 1e-6f) : 0.f;
      acc[0][j] += px - f * dx;
      acc[1][j] += py - f * dy;
      acc[2][j] += pz - f * dz;
    }
  }
  int pbase = ((n >> 4) * 48) + (n & 15);
#pragma unroll
  for (int v = 0; v < 3; ++v) {
    uint4 vv;
    vv.x = packhl(acc[v][0] * (1.f / 20.f));
    vv.y = packhl(acc[v][1] * (1.f / 20.f));
    vv.z = packhl(acc[v][2] * (1.f / 20.f));
    vv.w = packhl(acc[v][3] * (1.f / 20.f));
    *(uint4*)(Xp0 + ((size_t)b * P + pbase + v * 16) * 128 + og * 8) = vv;
  }
}

// ---------------------------------------------------------------------------
// K9: merge 8 out shadows -> d_out (mean over N).
// ---------------------------------------------------------------------------
__global__ __launch_bounds__(256) void out_merge_kernel(
    const float* __restrict__ outs, float* __restrict__ out) {
  int idx = blockIdx.x * 256 + threadIdx.x;  // 3072
  if (idx >= B * 384) return;
  float s = 0.f;
#pragma unroll
  for (int k = 0; k < 8; ++k) s += outs[k * 3072 + idx];
  out[idx] = s * (1.f / 2048.f);
}

// ---------------------------------------------------------------------------
// K4/K6/K8: MFMA VNT layer.  Bias for the pooled-concat half is now computed
// in-block (prologue): pooled mean staged from the 8 shadow copies into LDS,
// then bias[m][v] = dot(Wt[:,m], pooled[:,v]) with coalesced Wt loads.
// ---------------------------------------------------------------------------
template <int K2, bool HASPOOL, bool LAST>
__global__ __launch_bounds__(256, 4) void gemm_vnt_kernel(
    const unsigned short* __restrict__ Xp, const unsigned short* __restrict__ Wb,
    const float* __restrict__ ps, const float* __restrict__ Wt,
    unsigned short* __restrict__ Xq, float* __restrict__ pool,
    float* __restrict__ outs) {
  constexpr int KS = K2 / 32;
  constexpr int LDR = K2 + 8;   // halves; X-tile row stride
  constexpr int LDO = 132;      // floats; out-tile row stride
  __shared__ __align__(16) char smem[48 * LDO * 4];  // 25344 B, dual-purpose
  unsigned short* xt = (unsigned short*)smem;
  float* ot = (float*)smem;
  __shared__ float sb[768];
  __shared__ float spool[384];
  int tid = threadIdx.x;
  int bid = blockIdx.x;
  int b = bid >> 7;
  int nt = bid & 127;
  int p0 = nt * 48;

  // stage X tile [48][K2] -> LDS
  for (int ch = tid; ch < 48 * (K2 / 8); ch += 256) {
    int rp = ch / (K2 / 8), cc = ch % (K2 / 8);
    *(uint4*)(xt + rp * LDR + cc * 8) =
        *(const uint4*)(Xp + ((size_t)b * P + p0 + rp) * K2 + cc * 8);
  }
  if (HASPOOL) {
    // pooled mean (sum of 8 shadow copies) -> LDS
    for (int i = tid; i < 384; i += 256) {
      float x = 0.f;
#pragma unroll
      for (int k = 0; k < 8; ++k) x += ps[k * 3072 + b * 384 + i];
      spool[i] = x * (1.f / 2048.f);
    }
  }
  __syncthreads();
  if (HASPOOL) {
    // bias prologue: thread == stacked row m (0..127 = Wn, 128..255 = D)
    float s0 = 0.f, s1 = 0.f, s2 = 0.f;
#pragma unroll 4
    for (int c = 0; c < 128; ++c) {
      float x = Wt[c * 256 + tid];
      s0 = fmaf(x, spool[c * 3 + 0], s0);
      s1 = fmaf(x, spool[c * 3 + 1], s1);
      s2 = fmaf(x, spool[c * 3 + 2], s2);
    }
    sb[tid * 3 + 0] = s0;
    sb[tid * 3 + 1] = s1;
    sb[tid * 3 + 2] = s2;
    __syncthreads();
  }

  int w = tid >> 6, lane = tid & 63;
  int q = lane >> 4, cl = lane & 15;

  f32x4 acc[2][2][3] = {};  // [t][pd][v]
  const unsigned short* wbase = Wb + (size_t)cl * K2 + q * 8;

  bf16x8 acur[2][2], anxt[2][2];
#pragma unroll
  for (int t = 0; t < 2; ++t)
#pragma unroll
    for (int pd = 0; pd < 2; ++pd)
      acur[t][pd] = *(const bf16x8*)(wbase + (size_t)(32 * w + 16 * t + 128 * pd) * K2);

#pragma unroll
  for (int ks = 0; ks < KS; ++ks) {
    if (ks + 1 < KS) {
#pragma unroll
      for (int t = 0; t < 2; ++t)
#pragma unroll
        for (int pd = 0; pd < 2; ++pd)
          anxt[t][pd] = *(const bf16x8*)(wbase +
              (size_t)(32 * w + 16 * t + 128 * pd) * K2 + (ks + 1) * 32);
    }
    bf16x8 bb[3];
#pragma unroll
    for (int v = 0; v < 3; ++v)
      bb[v] = *(const bf16x8*)(xt + (v * 16 + cl) * LDR + ks * 32 + q * 8);
#pragma unroll
    for (int t = 0; t < 2; ++t)
#pragma unroll
      for (int pd = 0; pd < 2; ++pd)
#pragma unroll
        for (int v = 0; v < 3; ++v)
          acc[t][pd][v] = __builtin_amdgcn_mfma_f32_16x16x32_bf16(
              acur[t][pd], bb[v], acc[t][pd][v], 0, 0, 0);
#pragma unroll
    for (int t = 0; t < 2; ++t)
#pragma unroll
      for (int pd = 0; pd < 2; ++pd)
        acur[t][pd] = anxt[t][pd];
  }
  __syncthreads();  // X-tile dead; buffer becomes the fp32 out-tile

#pragma unroll
  for (int t = 0; t < 2; ++t) {
    float res[3][4];
#pragma unroll
    for (int r = 0; r < 4; ++r) {
      int o = 32 * w + 16 * t + 4 * q + r;
      float pv[3], dvv[3];
#pragma unroll
      for (int v = 0; v < 3; ++v) {
        pv[v] = acc[t][0][v][r] + (HASPOOL ? sb[o * 3 + v] : 0.f);
        dvv[v] = acc[t][1][v][r] + (HASPOOL ? sb[(128 + o) * 3 + v] : 0.f);
      }
      float dot = fmaf(pv[0], dvv[0], fmaf(pv[1], dvv[1], pv[2] * dvv[2]));
      float dns = fmaf(dvv[0], dvv[0], fmaf(dvv[1], dvv[1], dvv[2] * dvv[2]));
      float f = (dot < 0.f) ? dot / (dns + 1e-6f) : 0.f;
#pragma unroll
      for (int v = 0; v < 3; ++v) res[v][r] = pv[v] - f * dvv[v];
    }
    int o0 = 32 * w + 16 * t + 4 * q;
#pragma unroll
    for (int v = 0; v < 3; ++v) {
      f32x4 rv = {res[v][0], res[v][1], res[v][2], res[v][3]};
      *(f32x4*)(ot + (v * 16 + cl) * LDO + o0) = rv;
    }
  }
  __syncthreads();

  int shadow = (nt & 7) * 3072;
  for (int s = tid; s < 384; s += 256) {
    int o = s / 3, v = s % 3;
    float a2 = 0.f;
#pragma unroll
    for (int c = 0; c < 16; ++c) a2 += ot[(v * 16 + c) * LDO + o];
    if (LAST) atomicAdd(outs + shadow + b * 384 + s, a2);
    else      atomicAdd(pool + shadow + b * 384 + s, a2);
  }

  if (!LAST) {
    for (int s = tid; s < 1536; s += 256) {
      int pix = s >> 5, c4 = s & 31;
      const float* src = ot + pix * LDO + c4 * 4;
      uint4 vv;
      vv.x = packhl(src[0]);
      vv.y = packhl(src[1]);
      vv.z = packhl(src[2]);
      vv.w = packhl(src[3]);
      *(uint4*)(Xq + ((size_t)b * P + p0 + pix) * 256 + c4 * 8) = vv;
    }
  }
}

// ---------------------------------------------------------------------------
// launch
// ---------------------------------------------------------------------------
extern "C" void kernel_launch(void* const* d_in, const int* in_sizes, int n_in,
                              void* d_out, int out_size, void* d_ws, size_t ws_size,
                              hipStream_t stream) {
  (void)in_sizes; (void)n_in; (void)out_size; (void)ws_size;
  const float* pc   = (const float*)d_in[0];
  const float* Wpos = (const float*)d_in[1];
  const float* Dpos = (const float*)d_in[2];
  const float* W1   = (const float*)d_in[3];
  const float* D1   = (const float*)d_in[4];
  const float* W2   = (const float*)d_in[5];
  const float* D2   = (const float*)d_in[6];
  const float* W3   = (const float*)d_in[7];
  const float* D3   = (const float*)d_in[8];
  float* out = (float*)d_out;
  float* ws  = (float*)d_ws;

  prep_kernel<<<PREP_BLOCKS, 256, 0, stream>>>(Wpos, W1, D1, W2, D2, W3, D3, ws);
  knn_kernel<<<dim3(N / 4, B), 256, 0, stream>>>(pc, (int*)(ws + OIDX));
  edge_pos_kernel<<<dim3(16, 8, 8), 256, 0, stream>>>(
      pc, (const int*)(ws + OIDX), ws + OWNPOS, Dpos,
      (unsigned short*)(ws + OXP0));
  // layer1: K2=128 -> Xp1 + ps1 shadows
  gemm_vnt_kernel<128, false, false><<<1024, 256, 0, stream>>>(
      (const unsigned short*)(ws + OXP0), (const unsigned short*)(ws + OWB1),
      nullptr, nullptr, (unsigned short*)(ws + OXP1), ws + OPS1, nullptr);
  // layer2: bias prologue from ps1 + WT2 -> Xp2 + ps2 shadows
  gemm_vnt_kernel<256, true, false><<<1024, 256, 0, stream>>>(
      (const unsigned short*)(ws + OXP1), (const unsigned short*)(ws + OWB2),
      ws + OPS1, ws + OWT2, (unsigned short*)(ws + OXP2), ws + OPS2, nullptr);
  // layer3: bias prologue from ps2 + WT3 -> out shadows
  gemm_vnt_kernel<256, true, true><<<1024, 256, 0, stream>>>(
      (const unsigned short*)(ws + OXP2), (const unsigned short*)(ws + OWB3),
      ws + OPS2, ws + OWT3, nullptr, nullptr, ws + OOUTS);
  out_merge_kernel<<<12, 256, 0, stream>>>(ws + OOUTS, out);
}